// Round 7
// baseline (102.188 us; speedup 1.0000x reference)
//
#include <hip/hip_runtime.h>

#define NQ 32768
#define NC 8192
#define CFEAT 128
#define CSPLIT 64
#define TILE (NC / CSPLIT)   // 128 coords per split
#define BLK 256
#define QPT 16               // queries per thread (phase 1) — amortizes LDS
#define QPB (BLK * QPT)      // 4096 queries per block
#define GX (NQ / QPB)        // 8 -> phase-1 grid (8, 64) = 512 blocks (2/CU)

// ws layout: [0, 8 MB) f32 bestd[NQ][CSPLIT] ([q][s]: phase-2 wave reads one
// 256 B row per query — R2-proven; phase-1 scatter-stores are L2-absorbed);
// then float4 ctab[NC] (128 KB).
//
// NUMERICS IS FROZEN (R3/R4 lesson): the distance chain MUST be exactly
//   t = mul(cx', px); t = fma(cy', py, t); t = fma(cz', pz, t); d = cc + t
// with ctab entry (-2cx, -2cy, -2cz, ((cx*cx + cy*cy) + cz*cz)).
// Flip-free vs np's argmin (R0/R2/R5/R6: absmax 0.0). The 3-fma variant
// flips near-tie queries (R3/R4: 4.047). pk halves run the same IEEE-RN
// sequence -> bits unchanged whether compiler emits pk or scalarizes.
// Phase 2 consumes the SAME stored ctab bits (R1 lesson).
//
// STRUCTURE LESSONS:
//  R5: phase 2 stays wave-per-query, 32768 waves — TLP > coalescing polish.
//  R6: phase 1 was LDS-pipe-bound (512 ds_read_b128/block x 12 cyc on one
//      pipe/CU; 8 blocks/CU = ~20 us), NOT VALU-bound — which is why pk
//      packing alone was neutral. Fix: QPT 4->16 cuts blocks/CU to 2 ->
//      LDS ~5 us, packed VALU ~8.5 us -> VALU-bound ~9-10 us.
#define BESTD_OFF 0
#define CTAB_OFF ((size_t)NQ * CSPLIT * 4)

typedef float f32x2 __attribute__((ext_vector_type(2)));

// Phase 1: per-split min DISTANCE only — no index tracking.
// Packed inner loop: per 2 coords per query
//   v_pk_mul + v_pk_fma + v_pk_fma + v_pk_add + v_min3 = 5 insts (was 9).
__global__ __launch_bounds__(BLK, 2) void argmin_split(
    const float* __restrict__ coords, const float* __restrict__ points,
    float* __restrict__ bestd, float4* __restrict__ ctab) {
  // Pair-interleaved LDS ctab: A[p]=(x0,x1,y0,y1), B[p]=(z0,z1,w0,w1) for
  // coords (base+2p, base+2p+1). One b128 read each; halves are aligned
  // VGPR pairs -> direct v_pk operands. (R6-verified staging.)
  __shared__ float4 sA[TILE / 2];
  __shared__ float4 sB[TILE / 2];

  const int s = blockIdx.y;
  const int base = s * TILE;

  if (threadIdx.x < TILE) {
    const int i = base + threadIdx.x;
    const float cx = coords[i * 3 + 0];
    const float cy = coords[i * 3 + 1];
    const float cz = coords[i * 3 + 2];
    float xx = cx * cx, yy = cy * cy, zz = cz * cz;
    // Opaque barrier: forbid contracting these products into the adds.
    asm volatile("" : "+v"(xx), "+v"(yy), "+v"(zz));
    const float cc = (xx + yy) + zz;
    const float4 e = make_float4(-2.0f * cx, -2.0f * cy, -2.0f * cz, cc);
    const int p = threadIdx.x >> 1, hi = threadIdx.x & 1;
    float* a = (float*)&sA[p];
    float* b = (float*)&sB[p];
    a[0 + hi] = e.x;  a[2 + hi] = e.y;
    b[0 + hi] = e.z;  b[2 + hi] = e.w;
    if (blockIdx.x == 0) ctab[i] = e;   // persist exact bits for phase 2
  }

  const int q0 = blockIdx.x * QPB + threadIdx.x;
  // Points kept SCALAR (pk broadcasts a scalar VGPR to both halves via
  // op_sel) to hold VGPR pressure ~90 at QPT=16.
  float px[QPT], py[QPT], pz[QPT], best[QPT];
  #pragma unroll
  for (int k = 0; k < QPT; ++k) {
    const int q = q0 + k * BLK;
    px[k] = points[q * 3 + 0];
    py[k] = points[q * 3 + 1];
    pz[k] = points[q * 3 + 2];
    best[k] = __builtin_inff();
  }
  __syncthreads();

  #pragma unroll 2
  for (int p = 0; p < TILE / 2; ++p) {
    const float4 a = sA[p];          // uniform addr -> broadcast ds_read_b128
    const float4 b = sB[p];
    const f32x2 X = {a.x, a.y}, Y = {a.z, a.w};
    const f32x2 Z = {b.x, b.y}, W = {b.z, b.w};
    #pragma unroll
    for (int k = 0; k < QPT; ++k) {
      f32x2 t = X * (f32x2){px[k], px[k]};               // v_pk_mul_f32 (RN)
      t = __builtin_elementwise_fma(Y, (f32x2){py[k], py[k]}, t);  // pk_fma
      t = __builtin_elementwise_fma(Z, (f32x2){pz[k], pz[k]}, t);  // pk_fma
      const f32x2 d = W + t;                             // v_pk_add_f32 (RN)
      best[k] = fminf(fminf(best[k], d.x), d.y);         // v_min3_f32 (exact)
    }
  }

  #pragma unroll
  for (int k = 0; k < QPT; ++k) {
    const int q = q0 + k * BLK;
    bestd[(size_t)q * CSPLIT + s] = best[k];
  }
}

// Phase 2 (R2-proven, verbatim): one wave per query — reduce 64 split-mins
// (shfl min + ballot/ffs -> lowest winning split); equality-rescan that
// split's 128 coords from the SHARED global ctab (same bits + same frozen
// scalar chain -> hit guaranteed; first match = lowest coord). Tiebreak ==
// np.argmin's global first-index. Gather feature row, 64 lanes x float2.
__global__ __launch_bounds__(256) void rescan_gather(
    const float4* __restrict__ ctab, const float* __restrict__ points,
    const float* __restrict__ bestd, const float* __restrict__ feature,
    float2* __restrict__ out) {
  const int q = blockIdx.x * 4 + (threadIdx.x >> 6);
  const int l = threadIdx.x & 63;

  // lane l holds split l's min — 256 B coalesced read per wave
  const float v = bestd[(size_t)q * CSPLIT + l];
  float m = v;
  #pragma unroll
  for (int off = 32; off; off >>= 1) m = fminf(m, __shfl_xor(m, off, 64));
  const unsigned long long bs = __ballot(v == m);
  const int sstar = __ffsll(bs) - 1;            // lowest split attaining min

  const float qx = points[q * 3 + 0];           // wave-uniform
  const float qy = points[q * 3 + 1];
  const float qz = points[q * 3 + 2];
  const int b2 = sstar * TILE;

  const float4 c0 = ctab[b2 + l];               // coalesced, lanes consecutive
  const float4 c1 = ctab[b2 + 64 + l];
  float t0 = __fmul_rn(c0.x, qx);                      // FROZEN CHAIN (R2)
  t0 = __fmaf_rn(c0.y, qy, t0);
  t0 = __fmaf_rn(c0.z, qz, t0);
  const float d0 = __fadd_rn(c0.w, t0);
  float t1 = __fmul_rn(c1.x, qx);
  t1 = __fmaf_rn(c1.y, qy, t1);
  t1 = __fmaf_rn(c1.z, qz, t1);
  const float d1 = __fadd_rn(c1.w, t1);

  const unsigned long long b0 = __ballot(d0 == m);
  const unsigned long long b1 = __ballot(d1 == m);
  int off_in;
  if (b0 | b1) {
    off_in = b0 ? (__ffsll(b0) - 1) : (64 + __ffsll(b1) - 1);
  } else {
    // Defense in depth (should be unreachable): true argmin over the 128
    // rescanned candidates, first-index tiebreak.
    float dm = fminf(d0, d1);
    int im = (d0 <= d1) ? l : (64 + l);
    #pragma unroll
    for (int off = 32; off; off >>= 1) {
      const float od = __shfl_xor(dm, off, 64);
      const int oi = __shfl_xor(im, off, 64);
      if (od < dm || (od == dm && oi < im)) { dm = od; im = oi; }
    }
    off_in = im;
  }
  const int idx = b2 + off_in;

  const float2* fr = (const float2*)(feature + (size_t)idx * CFEAT);
  out[(size_t)q * (CFEAT / 2) + l] = fr[l];
}

extern "C" void kernel_launch(void* const* d_in, const int* in_sizes, int n_in,
                              void* d_out, int out_size, void* d_ws, size_t ws_size,
                              hipStream_t stream) {
  const float* coords  = (const float*)d_in[0];   // [8192, 3]
  const float* feature = (const float*)d_in[1];   // [8192, 128]
  const float* points  = (const float*)d_in[2];   // [32768, 3]
  float2* out = (float2*)d_out;                   // [32768, 128]

  float* bestd = (float*)((char*)d_ws + BESTD_OFF);
  float4* ctab = (float4*)((char*)d_ws + CTAB_OFF);

  dim3 grid1(GX, CSPLIT);                         // (8, 64) = 512 blocks
  argmin_split<<<grid1, BLK, 0, stream>>>(coords, points, bestd, ctab);

  rescan_gather<<<NQ / 4, 256, 0, stream>>>(ctab, points, bestd, feature,
                                            out);
}